// Round 7
// baseline (600.740 us; speedup 1.0000x reference)
//
#include <hip/hip_runtime.h>
#include <math.h>

#define T_TOK 2048
#define DDIM 1024
#define HDIM 4096
#define NEXP 8
#define NPRIME 8192            // 2*HDIM interleaved g/v cols per expert
#define KTOT (NEXP * HDIM)     // 32768
#define NSPLIT 8

typedef unsigned short u16;
typedef __attribute__((ext_vector_type(4))) float f32x4;
typedef __attribute__((ext_vector_type(8))) __bf16 bf16x8;
typedef __attribute__((ext_vector_type(8))) unsigned short u16x8;
typedef __attribute__((ext_vector_type(4))) unsigned short u16x4;

__device__ __forceinline__ u16 f2bf(float f) {
  unsigned int u = __builtin_bit_cast(unsigned int, f);
  u += 0x7fffu + ((u >> 16) & 1u);   // round-to-nearest-even
  return (u16)(u >> 16);
}

__device__ __forceinline__ void stage16(const u16* g, u16* l) {
  __builtin_amdgcn_global_load_lds((__attribute__((address_space(1))) void*)g,
                                   (__attribute__((address_space(3))) void*)l,
                                   16, 0, 0);
}

// ---------------- prep: x fp32 -> bf16 ----------------
__global__ void cvt_x_kernel(const float* __restrict__ x, u16* __restrict__ xb) {
  int i = (blockIdx.x * 256 + threadIdx.x) * 8;
  float4 a = *(const float4*)(x + i);
  float4 b = *(const float4*)(x + i + 4);
  u16x8 o;
  o[0] = f2bf(a.x); o[1] = f2bf(a.y); o[2] = f2bf(a.z); o[3] = f2bf(a.w);
  o[4] = f2bf(b.x); o[5] = f2bf(b.y); o[6] = f2bf(b.z); o[7] = f2bf(b.w);
  *(u16x8*)(xb + i) = o;
}

// ---------------- prep: transpose+cvt all experts ----------------
__global__ void transpose_all_kernel(const float* __restrict__ Wg,
                                     const float* __restrict__ Wv,
                                     const float* __restrict__ Wo,
                                     u16* __restrict__ wgvT, u16* __restrict__ woT2) {
  __shared__ float lds[64][65];
  const int bid = blockIdx.x;           // 24576 = 8e * 3mat * 1024 tiles
  const int e = bid / 3072;
  const int r = bid % 3072;
  const int which = r >> 10;            // 0=Wg 1=Wv 2=Wo
  const int tt = r & 1023;
  const float* src; int R, C;
  if (which == 2) { src = Wo + (size_t)e * HDIM * DDIM; R = HDIM; C = DDIM; }
  else            { src = (which ? Wv : Wg) + (size_t)e * DDIM * HDIM; R = DDIM; C = HDIM; }
  const int nrt = R >> 6;
  const int r0 = (tt % nrt) << 6, c0 = (tt / nrt) << 6;
  const int tid = threadIdx.x;
#pragma unroll
  for (int i = 0; i < 4; ++i) {
    int f4 = tid + 256 * i;
    int row = f4 >> 4, c4 = (f4 & 15) << 2;
    float4 v = *(const float4*)(src + (size_t)(r0 + row) * C + c0 + c4);
    lds[row][c4] = v.x; lds[row][c4 + 1] = v.y; lds[row][c4 + 2] = v.z; lds[row][c4 + 3] = v.w;
  }
  __syncthreads();
#pragma unroll
  for (int i = 0; i < 4; ++i) {
    int f4 = tid + 256 * i;
    int cc = f4 >> 4, r4 = (f4 & 15) << 2;
    u16x4 o;
    o[0] = f2bf(lds[r4][cc]);     o[1] = f2bf(lds[r4 + 1][cc]);
    o[2] = f2bf(lds[r4 + 2][cc]); o[3] = f2bf(lds[r4 + 3][cc]);
    u16* dst;
    if (which == 2) {
      dst = woT2 + (size_t)(c0 + cc) * KTOT + e * HDIM + r0 + r4;
    } else {
      int h = c0 + cc;
      int rowp = ((h >> 4) << 5) + which * 16 + (h & 15);
      dst = wgvT + (size_t)e * NPRIME * DDIM + (size_t)rowp * DDIM + r0 + r4;
    }
    *(u16x4*)dst = o;
  }
}

// =================================================================
// GEMM core: BM=256, BN=256, BK=32, 8 waves (2M x 4N), wave tile 128x64.
// 4-slot LDS ring (32 KB/slot). Software-pipelined: ds_reads issued one
// phase AHEAD of their consuming MFMA (lgkmcnt(6) drains only the
// previous phase's reads). Stage tile t+3 (A at ph0, B at ph1);
// counted vmcnt(4)+barrier at ph1 end makes tile t+2 collectively
// visible. TAIL FIX (R6 race): once staging stops, vmcnt(4) is a no-op
// with only 4 loads left in queue -> tile NT-1 was never drained.
// Now: vmcnt(4) while staging continues, vmcnt(0) after (fires once).
// =================================================================

template<int KS>
__device__ __forceinline__ void gemm_loop(const u16* Ab, const u16* Bb,
                                          int Am0, int Bn0, int kbase, int NT,
                                          u16* lds, int tid, f32x4 (&acc)[8][4]) {
  const int lane = tid & 63;
  const int wave = tid >> 6;
  const int wm = wave >> 2, wn = wave & 3;
  const int l15 = lane & 15, lkq = lane >> 4;

  // staging descriptors (per thread: 2 chunks A, 2 chunks B per tile)
  const int cA0 = tid, cA1 = tid + 512;       // of 1024 16B-chunks (A)
  auto srcA = [&](int c) {
    int row = c >> 2, s = c & 3;
    int sx = s ^ (row & 3) ^ ((row >> 2) & 3);
    return Ab + (size_t)(Am0 + row) * KS + kbase + (sx << 3);
  };
  auto srcB = [&](int c) {
    int row = c >> 2, s = c & 3;
    int sx = s ^ (row & 3) ^ ((row >> 2) & 3);
    return Bb + (size_t)(Bn0 + row) * KS + kbase + (sx << 3);
  };
  const u16* gA0 = srcA(cA0); const u16* gA1 = srcA(cA1);
  const u16* gB0 = srcB(cA0); const u16* gB1 = srcB(cA1);

  auto stageA = [&](int t) {
    u16* sl_ = lds + ((t & 3) << 14);
    int k0 = t << 5;
    stage16(gA0 + k0, sl_ + cA0 * 8);
    stage16(gA1 + k0, sl_ + cA1 * 8);
  };
  auto stageB = [&](int t) {
    u16* sl_ = lds + ((t & 3) << 14);
    int k0 = t << 5;
    stage16(gB0 + k0, sl_ + 8192 + cA0 * 8);
    stage16(gB1 + k0, sl_ + 8192 + cA1 * 8);
  };

  auto ldA = [&](const u16* sl_, int mf) -> bf16x8 {
    int row = wm * 128 + mf * 16 + l15;
    int s = lkq ^ (row & 3) ^ ((row >> 2) & 3);
    return *(const bf16x8*)(sl_ + row * 32 + s * 8);
  };
  auto ldB = [&](const u16* sl_, int nf) -> bf16x8 {
    int row = wn * 64 + nf * 16 + l15;
    int s = lkq ^ (row & 3) ^ ((row >> 2) & 3);
    return *(const bf16x8*)(sl_ + 8192 + row * 32 + s * 8);
  };

  bf16x8 af[8], bf[4], bfn[4];

  // prologue: tiles 0,1,2 staged; collective-drain tiles 0,1; pre-read tile 0
  stageA(0); stageB(0); stageA(1); stageB(1); stageA(2); stageB(2);
  asm volatile("s_waitcnt vmcnt(4)" ::: "memory");
  __builtin_amdgcn_s_barrier();
#pragma unroll
  for (int mf = 0; mf < 4; ++mf) af[mf] = ldA(lds, mf);
#pragma unroll
  for (int nf = 0; nf < 4; ++nf) bf[nf] = ldB(lds, nf);

#pragma unroll 1
  for (int t = 0; t < NT; ++t) {
    u16* sc = lds + ((t & 3) << 14);
    const int tn = (t + 1 < NT) ? t + 1 : t;   // clamp: keeps lgkm counts uniform
    u16* sn = lds + ((tn & 3) << 14);

    // ---- phase 0: reads {af4-7(t), bfn01(t+1)} ; stage A(t+3) ; MFMA m0-3
#pragma unroll
    for (int mf = 0; mf < 4; ++mf) af[4 + mf] = ldA(sc, 4 + mf);
    bfn[0] = ldB(sn, 0); bfn[1] = ldB(sn, 1);
    if (t + 3 < NT) stageA(t + 3);
    asm volatile("s_waitcnt lgkmcnt(6)" ::: "memory");
    __builtin_amdgcn_sched_barrier(0);
    __builtin_amdgcn_s_setprio(1);
#pragma unroll
    for (int mf = 0; mf < 4; ++mf)
#pragma unroll
      for (int nf = 0; nf < 4; ++nf)
        acc[mf][nf] = __builtin_amdgcn_mfma_f32_16x16x32_bf16(af[mf], bf[nf], acc[mf][nf], 0, 0, 0);
    __builtin_amdgcn_s_setprio(0);
    __builtin_amdgcn_s_barrier();

    // ---- phase 1: reads {bfn23(t+1), af0-3(t+1)} ; stage B(t+3) ; MFMA m4-7
    bfn[2] = ldB(sn, 2); bfn[3] = ldB(sn, 3);
#pragma unroll
    for (int mf = 0; mf < 4; ++mf) af[mf] = ldA(sn, mf);
    if (t + 3 < NT) stageB(t + 3);
    asm volatile("s_waitcnt lgkmcnt(6)" ::: "memory");
    __builtin_amdgcn_sched_barrier(0);
    __builtin_amdgcn_s_setprio(1);
#pragma unroll
    for (int mf = 0; mf < 4; ++mf)
#pragma unroll
      for (int nf = 0; nf < 4; ++nf)
        acc[4 + mf][nf] = __builtin_amdgcn_mfma_f32_16x16x32_bf16(af[4 + mf], bf[nf], acc[4 + mf][nf], 0, 0, 0);
    __builtin_amdgcn_s_setprio(0);
    // collective residency of tile t+2 after the barrier. TAIL FIX: when
    // staging has stopped, only tile t+2's 4 loads remain in the queue, so
    // vmcnt(4) would be a no-op -> must drain fully (fires exactly once).
    if (t + 3 < NT) { asm volatile("s_waitcnt vmcnt(4)" ::: "memory"); }
    else            { asm volatile("s_waitcnt vmcnt(0)" ::: "memory"); }
    __builtin_amdgcn_s_barrier();
    bf[0] = bfn[0]; bf[1] = bfn[1]; bf[2] = bfn[2]; bf[3] = bfn[3];
  }
}

// ---------------- GEMM A: h = (gelu(x@Wg) * (x@Wv)) * scale * cw ----------------
__global__ void __launch_bounds__(512, 2)
gemm_gv_kernel(const u16* __restrict__ xb, const u16* __restrict__ wgvT,
               const float* __restrict__ disp, const float* __restrict__ comb,
               const float* __restrict__ scale, u16* __restrict__ h) {
  __shared__ u16 lds[65536];

  // XCD swizzle: 2048 wgs, expert e -> XCD e
  const int bid = blockIdx.x;
  const int wg = (bid & 7) * 256 + (bid >> 3);
  const int e  = wg >> 8;
  const int rr = wg & 255;
  const int nt = rr >> 3;          // 0..31 (N' tiles of 256)
  const int mt = rr & 7;           // 0..7  (M tiles of 256)

  const int tid = threadIdx.x;
  const int lane = tid & 63;
  const int wave = tid >> 6;
  const int wm = wave >> 2, wn = wave & 3;
  const int l15 = lane & 15, lkq = lane >> 4;

  const u16* Bb = wgvT + (size_t)e * NPRIME * DDIM;
  const int Am0 = mt * 256;
  const int Bn0 = nt * 256;

  f32x4 acc[8][4] = {};
  gemm_loop<DDIM>(xb, Bb, Am0, Bn0, 0, DDIM / 32, lds, tid, acc);

  const float s_e = scale[e];
  const int hbase = nt * 128 + wn * 32;   // H-col base within expert
#pragma unroll
  for (int a = 0; a < 8; ++a) {
#pragma unroll
    for (int r = 0; r < 4; ++r) {
      const int t = Am0 + wm * 128 + a * 16 + lkq * 4 + r;
      const float dv = disp[t * NEXP + e];
      const float cv = comb[t * NEXP + e];
      const float s = (dv > 0.0f) ? cv * s_e : 0.0f;
#pragma unroll
      for (int jj = 0; jj < 2; ++jj) {
        const float g = acc[a][2 * jj][r];
        const float v = acc[a][2 * jj + 1][r];
        const float ge = 0.5f * g * (1.0f + erff(g * 0.70710678f));
        h[(size_t)t * KTOT + e * HDIM + hbase + jj * 16 + l15] = f2bf(ge * v * s);
      }
    }
  }
}

// ---------------- GEMM B: P[kz] = h[T][EH] @ woT2[D][EH]^T (split-K 8) ----------------
__global__ void __launch_bounds__(512, 2)
gemm_out_kernel(const u16* __restrict__ hb, const u16* __restrict__ woT2,
                float* __restrict__ P) {
  __shared__ u16 lds[65536];

  const int bid = blockIdx.x;          // 256 wgs
  const int wg = (bid & 7) * 32 + (bid >> 3);
  const int kz = wg >> 5;              // 0..7, one per XCD
  const int rr = wg & 31;
  const int nt = rr >> 3;              // 0..3 (D tiles of 256)
  const int mt = rr & 7;               // 0..7 (token tiles of 256)

  const int tid = threadIdx.x;
  const int lane = tid & 63;
  const int wave = tid >> 6;
  const int wm = wave >> 2, wn = wave & 3;
  const int l15 = lane & 15, lkq = lane >> 4;

  const int Am0 = mt * 256;
  const int Bn0 = nt * 256;
  const int kbase = kz * (KTOT / NSPLIT);   // 4096 per split

  f32x4 acc[8][4] = {};
  gemm_loop<KTOT>(hb, woT2, Am0, Bn0, kbase, (KTOT / NSPLIT) / 32, lds, tid, acc);

  float* Pp = P + (size_t)kz * (T_TOK * DDIM);
#pragma unroll
  for (int a = 0; a < 8; ++a) {
#pragma unroll
    for (int r = 0; r < 4; ++r) {
      const int t = Am0 + wm * 128 + a * 16 + lkq * 4 + r;
#pragma unroll
      for (int nf = 0; nf < 4; ++nf)
        Pp[(size_t)t * DDIM + Bn0 + wn * 64 + nf * 16 + l15] = acc[a][nf][r];
    }
  }
}

// ---------------- final: out = sum of NSPLIT partials ----------------
__global__ void reduce_out_kernel(const float* __restrict__ P, float* __restrict__ out) {
  int i = blockIdx.x * 256 + threadIdx.x;
  float4 a = ((const float4*)P)[i];
#pragma unroll
  for (int s = 1; s < NSPLIT; ++s) {
    float4 b = ((const float4*)P)[i + s * (T_TOK * DDIM / 4)];
    a.x += b.x; a.y += b.y; a.z += b.z; a.w += b.w;
  }
  ((float4*)out)[i] = a;
}

extern "C" void kernel_launch(void* const* d_in, const int* in_sizes, int n_in,
                              void* d_out, int out_size, void* d_ws, size_t ws_size,
                              hipStream_t stream) {
  const float* tokens = (const float*)d_in[0];
  const float* disp   = (const float*)d_in[1];
  const float* comb   = (const float*)d_in[2];
  const float* Wg     = (const float*)d_in[3];
  const float* Wv     = (const float*)d_in[4];
  const float* Wo     = (const float*)d_in[5];
  const float* scale  = (const float*)d_in[6];
  float* out = (float*)d_out;

  char* ws = (char*)d_ws;
  const size_t MB = 1024 * 1024;
  u16* xb    = (u16*)(ws);              // 4 MB   [T][D] bf16
  u16* wgvT  = (u16*)(ws + 4   * MB);   // 128 MB [E][8192][D] interleaved g/v
  u16* woT2  = (u16*)(ws + 132 * MB);   // 64 MB  [D][E*H]
  u16* hbuf  = (u16*)(ws + 196 * MB);   // 128 MB [T][E*H]
  float* P   = (float*)(ws + 324 * MB); // 64 MB  NSPLIT x [T][D] fp32

  cvt_x_kernel<<<1024, 256, 0, stream>>>(tokens, xb);
  transpose_all_kernel<<<24576, 256, 0, stream>>>(Wg, Wv, Wo, wgvT, woT2);
  gemm_gv_kernel<<<2048, 512, 0, stream>>>(xb, wgvT, disp, comb, scale, hbuf);
  gemm_out_kernel<<<256, 512, 0, stream>>>(hbuf, woT2, P);
  reduce_out_kernel<<<2048, 256, 0, stream>>>(P, out);
}

// Round 8
// 553.032 us; speedup vs baseline: 1.0863x; 1.0863x over previous
//
#include <hip/hip_runtime.h>
#include <math.h>

#define T_TOK 2048
#define DDIM 1024
#define HDIM 4096
#define NEXP 8
#define NPRIME 8192            // 2*HDIM interleaved g/v cols per expert
#define KTOT (NEXP * HDIM)     // 32768
#define NSPLIT 8

typedef unsigned short u16;
typedef __attribute__((ext_vector_type(4))) float f32x4;
typedef __attribute__((ext_vector_type(8))) __bf16 bf16x8;
typedef __attribute__((ext_vector_type(8))) unsigned short u16x8;
typedef __attribute__((ext_vector_type(4))) unsigned short u16x4;

__device__ __forceinline__ u16 f2bf(float f) {
  unsigned int u = __builtin_bit_cast(unsigned int, f);
  u += 0x7fffu + ((u >> 16) & 1u);   // round-to-nearest-even
  return (u16)(u >> 16);
}

__device__ __forceinline__ void stage16(const u16* g, u16* l) {
  __builtin_amdgcn_global_load_lds((__attribute__((address_space(1))) void*)g,
                                   (__attribute__((address_space(3))) void*)l,
                                   16, 0, 0);
}

// ---------------- prep: x fp32 -> bf16 ----------------
__global__ void cvt_x_kernel(const float* __restrict__ x, u16* __restrict__ xb) {
  int i = (blockIdx.x * 256 + threadIdx.x) * 8;
  float4 a = *(const float4*)(x + i);
  float4 b = *(const float4*)(x + i + 4);
  u16x8 o;
  o[0] = f2bf(a.x); o[1] = f2bf(a.y); o[2] = f2bf(a.z); o[3] = f2bf(a.w);
  o[4] = f2bf(b.x); o[5] = f2bf(b.y); o[6] = f2bf(b.z); o[7] = f2bf(b.w);
  *(u16x8*)(xb + i) = o;
}

// ---------------- prep: transpose+cvt all experts ----------------
__global__ void transpose_all_kernel(const float* __restrict__ Wg,
                                     const float* __restrict__ Wv,
                                     const float* __restrict__ Wo,
                                     u16* __restrict__ wgvT, u16* __restrict__ woT2) {
  __shared__ float lds[64][65];
  const int bid = blockIdx.x;           // 24576 = 8e * 3mat * 1024 tiles
  const int e = bid / 3072;
  const int r = bid % 3072;
  const int which = r >> 10;            // 0=Wg 1=Wv 2=Wo
  const int tt = r & 1023;
  const float* src; int R, C;
  if (which == 2) { src = Wo + (size_t)e * HDIM * DDIM; R = HDIM; C = DDIM; }
  else            { src = (which ? Wv : Wg) + (size_t)e * DDIM * HDIM; R = DDIM; C = HDIM; }
  const int nrt = R >> 6;
  const int r0 = (tt % nrt) << 6, c0 = (tt / nrt) << 6;
  const int tid = threadIdx.x;
#pragma unroll
  for (int i = 0; i < 4; ++i) {
    int f4 = tid + 256 * i;
    int row = f4 >> 4, c4 = (f4 & 15) << 2;
    float4 v = *(const float4*)(src + (size_t)(r0 + row) * C + c0 + c4);
    lds[row][c4] = v.x; lds[row][c4 + 1] = v.y; lds[row][c4 + 2] = v.z; lds[row][c4 + 3] = v.w;
  }
  __syncthreads();
#pragma unroll
  for (int i = 0; i < 4; ++i) {
    int f4 = tid + 256 * i;
    int cc = f4 >> 4, r4 = (f4 & 15) << 2;
    u16x4 o;
    o[0] = f2bf(lds[r4][cc]);     o[1] = f2bf(lds[r4 + 1][cc]);
    o[2] = f2bf(lds[r4 + 2][cc]); o[3] = f2bf(lds[r4 + 3][cc]);
    u16* dst;
    if (which == 2) {
      dst = woT2 + (size_t)(c0 + cc) * KTOT + e * HDIM + r0 + r4;
    } else {
      int h = c0 + cc;
      int rowp = ((h >> 4) << 5) + which * 16 + (h & 15);
      dst = wgvT + (size_t)e * NPRIME * DDIM + (size_t)rowp * DDIM + r0 + r4;
    }
    *(u16x4*)dst = o;
  }
}

// =================================================================
// GEMM core: BM=256, BN=256, BK=64, 8 waves (2M x 4N), wave tile 128x64.
// R5 skeleton (refcheck'd ledger) + ADDRESS STRENGTH-REDUCTION:
// all 24 ds_reads/K-tile = 4 precomputed per-lane bases (A/B x ks) +
// compile-time immediates (valid since row&7 == l15&7, invariant of
// mf/nf/wm/wn). Cuts in-loop VALU from ~170 to ~10 per K-tile.
// XOR-8 swizzle on [row][64] (128B rows) - measured 0 conflicts (R4/R5).
// =================================================================

template<int KS>
__device__ __forceinline__ void gemm_loop(const u16* Ab, const u16* Bb,
                                          int Am0, int Bn0, int kbase, int NT,
                                          u16* lds, int tid, f32x4 (&acc)[8][4]) {
  const int lane = tid & 63;
  const int wave = tid >> 6;
  const int wm = wave >> 2, wn = wave & 3;
  const int l15 = lane & 15, lkq = lane >> 4;

  // ---- staging descriptors (per thread: 2 chunks per unit, 4 units/tile)
  const int sl = tid & 7, rw = tid >> 3;          // rw 0..63
  const int slx = (sl ^ (rw & 7)) << 3;           // inverse-swizzled k-offset
  const int rb = (rw & 31) + ((rw >> 5) << 6);    // B base row
  const u16* pA = Ab + (size_t)(Am0 + rw) * KS + kbase + slx;
  const u16* pB = Bb + (size_t)(Bn0 + rb) * KS + kbase + slx;
  const int dA = rw * 64 + sl * 8;
  const int dB = 16384 + rb * 64 + sl * 8;

  auto SA0 = [&](int k, u16* slot) {
    stage16(pA + k, slot + dA);
    stage16(pA + (size_t)128 * KS + k, slot + dA + 128 * 64);
  };
  auto SA1 = [&](int k, u16* slot) {
    stage16(pA + (size_t)64 * KS + k, slot + dA + 64 * 64);
    stage16(pA + (size_t)192 * KS + k, slot + dA + 192 * 64);
  };
  auto SB0 = [&](int k, u16* slot) {
    stage16(pB + k, slot + dB);
    stage16(pB + (size_t)128 * KS + k, slot + dB + 128 * 64);
  };
  auto SB1 = [&](int k, u16* slot) {
    stage16(pB + (size_t)32 * KS + k, slot + dB + 32 * 64);
    stage16(pB + (size_t)160 * KS + k, slot + dB + 160 * 64);
  };

  // ---- strength-reduced read bases (elems). row&7 == l15&7 for all reads.
  const int swz0 = (lkq ^ (l15 & 7)) << 3;        // ks=0 slot
  const int swz1 = ((4 | lkq) ^ (l15 & 7)) << 3;  // ks=1 slot
  const int arow = (wm * 128 + l15) * 64;
  const int brow = 16384 + (wn * 64 + l15) * 64;
  const int a0 = arow + swz0, a1 = arow + swz1;
  const int b0 = brow + swz0, b1 = brow + swz1;

  // prologue: all of tile 0 into slot 0 (SA0,SB0 first -> vmcnt(4) drains them)
  SA0(0, lds); SB0(0, lds); SB1(0, lds); SA1(0, lds);
  asm volatile("s_waitcnt vmcnt(4)" ::: "memory");
  __builtin_amdgcn_s_barrier();

#pragma unroll 1
  for (int t = 0; t < NT; ++t) {
    const u16* s = lds + (t & 1) * 32768;
    u16* s2 = lds + ((t & 1) ^ 1) * 32768;
    const int kn = (t + 1) << 6;
    const bool more = (t + 1 < NT);
    bf16x8 af[4][2], bfr[4][2];

    // ---------- phase 0: read A-mh0 + B-nh0 ; stage SA0(t+1) ; MFMA m0-3 x n0-1
#pragma unroll
    for (int mf = 0; mf < 4; ++mf) {
      af[mf][0] = *(const bf16x8*)(s + a0 + mf * 1024);
      af[mf][1] = *(const bf16x8*)(s + a1 + mf * 1024);
    }
#pragma unroll
    for (int nf = 0; nf < 2; ++nf) {
      bfr[nf][0] = *(const bf16x8*)(s + b0 + nf * 1024);
      bfr[nf][1] = *(const bf16x8*)(s + b1 + nf * 1024);
    }
    if (more) SA0(kn, s2);
    __builtin_amdgcn_sched_barrier(0);
    __builtin_amdgcn_s_barrier();
    asm volatile("s_waitcnt lgkmcnt(0)" ::: "memory");
    __builtin_amdgcn_sched_barrier(0);
    __builtin_amdgcn_s_setprio(1);
#pragma unroll
    for (int ks = 0; ks < 2; ++ks)
#pragma unroll
      for (int mf = 0; mf < 4; ++mf)
#pragma unroll
        for (int nf = 0; nf < 2; ++nf)
          acc[mf][nf] = __builtin_amdgcn_mfma_f32_16x16x32_bf16(af[mf][ks], bfr[nf][ks], acc[mf][nf], 0, 0, 0);
    __builtin_amdgcn_s_setprio(0);
    if (more) { asm volatile("s_waitcnt vmcnt(4)" ::: "memory"); }
    else      { asm volatile("s_waitcnt vmcnt(2)" ::: "memory"); }
    __builtin_amdgcn_s_barrier();
    __builtin_amdgcn_sched_barrier(0);

    // ---------- phase 1: read B-nh1 ; stage SB0(t+1) ; MFMA m0-3 x n2-3
#pragma unroll
    for (int nf = 2; nf < 4; ++nf) {
      bfr[nf][0] = *(const bf16x8*)(s + b0 + nf * 1024);
      bfr[nf][1] = *(const bf16x8*)(s + b1 + nf * 1024);
    }
    if (more) SB0(kn, s2);
    __builtin_amdgcn_sched_barrier(0);
    __builtin_amdgcn_s_barrier();
    asm volatile("s_waitcnt lgkmcnt(0)" ::: "memory");
    __builtin_amdgcn_sched_barrier(0);
    __builtin_amdgcn_s_setprio(1);
#pragma unroll
    for (int ks = 0; ks < 2; ++ks)
#pragma unroll
      for (int mf = 0; mf < 4; ++mf)
#pragma unroll
        for (int nf = 2; nf < 4; ++nf)
          acc[mf][nf] = __builtin_amdgcn_mfma_f32_16x16x32_bf16(af[mf][ks], bfr[nf][ks], acc[mf][nf], 0, 0, 0);
    __builtin_amdgcn_s_setprio(0);
    if (more) { asm volatile("s_waitcnt vmcnt(4)" ::: "memory"); }
    else      { asm volatile("s_waitcnt vmcnt(0)" ::: "memory"); }
    __builtin_amdgcn_s_barrier();
    __builtin_amdgcn_sched_barrier(0);

    // ---------- phase 2: read A-mh1 ; stage SB1(t+1) ; MFMA m4-7 x n0-1
#pragma unroll
    for (int mf = 0; mf < 4; ++mf) {
      af[mf][0] = *(const bf16x8*)(s + a0 + 4096 + mf * 1024);
      af[mf][1] = *(const bf16x8*)(s + a1 + 4096 + mf * 1024);
    }
    if (more) SB1(kn, s2);
    __builtin_amdgcn_sched_barrier(0);
    __builtin_amdgcn_s_barrier();
    asm volatile("s_waitcnt lgkmcnt(0)" ::: "memory");
    __builtin_amdgcn_sched_barrier(0);
    __builtin_amdgcn_s_setprio(1);
#pragma unroll
    for (int ks = 0; ks < 2; ++ks)
#pragma unroll
      for (int mf = 0; mf < 4; ++mf)
#pragma unroll
        for (int nf = 0; nf < 2; ++nf)
          acc[4 + mf][nf] = __builtin_amdgcn_mfma_f32_16x16x32_bf16(af[mf][ks], bfr[nf][ks], acc[4 + mf][nf], 0, 0, 0);
    __builtin_amdgcn_s_setprio(0);
    __builtin_amdgcn_s_barrier();
    __builtin_amdgcn_sched_barrier(0);

    // ---------- phase 3: stage SA1(t+1) ; MFMA m4-7 x n2-3 (all regs cached)
    if (more) SA1(kn, s2);
    __builtin_amdgcn_s_setprio(1);
#pragma unroll
    for (int ks = 0; ks < 2; ++ks)
#pragma unroll
      for (int mf = 0; mf < 4; ++mf)
#pragma unroll
        for (int nf = 2; nf < 4; ++nf)
          acc[4 + mf][nf] = __builtin_amdgcn_mfma_f32_16x16x32_bf16(af[mf][ks], bfr[nf][ks], acc[4 + mf][nf], 0, 0, 0);
    __builtin_amdgcn_s_setprio(0);
    if (more) { asm volatile("s_waitcnt vmcnt(4)" ::: "memory"); }
    __builtin_amdgcn_s_barrier();
    __builtin_amdgcn_sched_barrier(0);
  }
}

// ---------------- GEMM A: h = (gelu(x@Wg) * (x@Wv)) * scale * cw ----------------
__global__ void __launch_bounds__(512, 2)
gemm_gv_kernel(const u16* __restrict__ xb, const u16* __restrict__ wgvT,
               const float* __restrict__ disp, const float* __restrict__ comb,
               const float* __restrict__ scale, u16* __restrict__ h) {
  __shared__ u16 lds[65536];

  // XCD swizzle: 2048 wgs, expert e -> XCD e
  const int bid = blockIdx.x;
  const int wg = (bid & 7) * 256 + (bid >> 3);
  const int e  = wg >> 8;
  const int rr = wg & 255;
  const int nt = rr >> 3;          // 0..31 (N' tiles of 256)
  const int mt = rr & 7;           // 0..7  (M tiles of 256)

  const int tid = threadIdx.x;
  const int lane = tid & 63;
  const int wave = tid >> 6;
  const int wm = wave >> 2, wn = wave & 3;
  const int l15 = lane & 15, lkq = lane >> 4;

  const u16* Bb = wgvT + (size_t)e * NPRIME * DDIM;
  const int Am0 = mt * 256;
  const int Bn0 = nt * 256;

  f32x4 acc[8][4] = {};
  gemm_loop<DDIM>(xb, Bb, Am0, Bn0, 0, DDIM / 64, lds, tid, acc);

  const float s_e = scale[e];
  const int hbase = nt * 128 + wn * 32;   // H-col base within expert
#pragma unroll
  for (int a = 0; a < 8; ++a) {
#pragma unroll
    for (int r = 0; r < 4; ++r) {
      const int t = Am0 + wm * 128 + a * 16 + lkq * 4 + r;
      const float dv = disp[t * NEXP + e];
      const float cv = comb[t * NEXP + e];
      const float s = (dv > 0.0f) ? cv * s_e : 0.0f;
#pragma unroll
      for (int jj = 0; jj < 2; ++jj) {
        const float g = acc[a][2 * jj][r];
        const float v = acc[a][2 * jj + 1][r];
        const float ge = 0.5f * g * (1.0f + erff(g * 0.70710678f));
        h[(size_t)t * KTOT + e * HDIM + hbase + jj * 16 + l15] = f2bf(ge * v * s);
      }
    }
  }
}

// ---------------- GEMM B: P[kz] = h[T][EH] @ woT2[D][EH]^T (split-K 8) ----------------
__global__ void __launch_bounds__(512, 2)
gemm_out_kernel(const u16* __restrict__ hb, const u16* __restrict__ woT2,
                float* __restrict__ P) {
  __shared__ u16 lds[65536];

  const int bid = blockIdx.x;          // 256 wgs
  const int wg = (bid & 7) * 32 + (bid >> 3);
  const int kz = wg >> 5;              // 0..7, one per XCD
  const int rr = wg & 31;
  const int nt = rr >> 3;              // 0..3 (D tiles of 256)
  const int mt = rr & 7;               // 0..7 (token tiles of 256)

  const int tid = threadIdx.x;
  const int lane = tid & 63;
  const int wave = tid >> 6;
  const int wm = wave >> 2, wn = wave & 3;
  const int l15 = lane & 15, lkq = lane >> 4;

  const int Am0 = mt * 256;
  const int Bn0 = nt * 256;
  const int kbase = kz * (KTOT / NSPLIT);   // 4096 per split

  f32x4 acc[8][4] = {};
  gemm_loop<KTOT>(hb, woT2, Am0, Bn0, kbase, (KTOT / NSPLIT) / 64, lds, tid, acc);

  float* Pp = P + (size_t)kz * (T_TOK * DDIM);
#pragma unroll
  for (int a = 0; a < 8; ++a) {
#pragma unroll
    for (int r = 0; r < 4; ++r) {
      const int t = Am0 + wm * 128 + a * 16 + lkq * 4 + r;
#pragma unroll
      for (int nf = 0; nf < 4; ++nf)
        Pp[(size_t)t * DDIM + Bn0 + wn * 64 + nf * 16 + l15] = acc[a][nf][r];
    }
  }
}

// ---------------- final: out = sum of NSPLIT partials ----------------
__global__ void reduce_out_kernel(const float* __restrict__ P, float* __restrict__ out) {
  int i = blockIdx.x * 256 + threadIdx.x;
  float4 a = ((const float4*)P)[i];
#pragma unroll
  for (int s = 1; s < NSPLIT; ++s) {
    float4 b = ((const float4*)P)[i + s * (T_TOK * DDIM / 4)];
    a.x += b.x; a.y += b.y; a.z += b.z; a.w += b.w;
  }
  ((float4*)out)[i] = a;
}

extern "C" void kernel_launch(void* const* d_in, const int* in_sizes, int n_in,
                              void* d_out, int out_size, void* d_ws, size_t ws_size,
                              hipStream_t stream) {
  const float* tokens = (const float*)d_in[0];
  const float* disp   = (const float*)d_in[1];
  const float* comb   = (const float*)d_in[2];
  const float* Wg     = (const float*)d_in[3];
  const float* Wv     = (const float*)d_in[4];
  const float* Wo     = (const float*)d_in[5];
  const float* scale  = (const float*)d_in[6];
  float* out = (float*)d_out;

  char* ws = (char*)d_ws;
  const size_t MB = 1024 * 1024;
  u16* xb    = (u16*)(ws);              // 4 MB   [T][D] bf16
  u16* wgvT  = (u16*)(ws + 4   * MB);   // 128 MB [E][8192][D] interleaved g/v
  u16* woT2  = (u16*)(ws + 132 * MB);   // 64 MB  [D][E*H]
  u16* hbuf  = (u16*)(ws + 196 * MB);   // 128 MB [T][E*H]
  float* P   = (float*)(ws + 324 * MB); // 64 MB  NSPLIT x [T][D] fp32

  cvt_x_kernel<<<1024, 256, 0, stream>>>(tokens, xb);
  transpose_all_kernel<<<24576, 256, 0, stream>>>(Wg, Wv, Wo, wgvT, woT2);
  gemm_gv_kernel<<<2048, 512, 0, stream>>>(xb, wgvT, disp, comb, scale, hbuf);
  gemm_out_kernel<<<256, 512, 0, stream>>>(hbuf, woT2, P);
  reduce_out_kernel<<<2048, 256, 0, stream>>>(P, out);
}

// Round 9
// 549.024 us; speedup vs baseline: 1.0942x; 1.0073x over previous
//
#include <hip/hip_runtime.h>
#include <math.h>

#define T_TOK 2048
#define DDIM 1024
#define HDIM 4096
#define NEXP 8
#define NPRIME 8192            // 2*HDIM interleaved g/v cols per expert
#define KTOT (NEXP * HDIM)     // 32768
#define NSPLIT 8

typedef unsigned short u16;
typedef __attribute__((ext_vector_type(4))) float f32x4;
typedef __attribute__((ext_vector_type(8))) __bf16 bf16x8;
typedef __attribute__((ext_vector_type(8))) unsigned short u16x8;
typedef __attribute__((ext_vector_type(4))) unsigned short u16x4;

__device__ __forceinline__ u16 f2bf(float f) {
  unsigned int u = __builtin_bit_cast(unsigned int, f);
  u += 0x7fffu + ((u >> 16) & 1u);   // round-to-nearest-even
  return (u16)(u >> 16);
}

__device__ __forceinline__ void stage16(const u16* g, u16* l) {
  __builtin_amdgcn_global_load_lds((__attribute__((address_space(1))) void*)g,
                                   (__attribute__((address_space(3))) void*)l,
                                   16, 0, 0);
}

// ---------------- prep: x fp32 -> bf16 ----------------
__global__ void cvt_x_kernel(const float* __restrict__ x, u16* __restrict__ xb) {
  int i = (blockIdx.x * 256 + threadIdx.x) * 8;
  float4 a = *(const float4*)(x + i);
  float4 b = *(const float4*)(x + i + 4);
  u16x8 o;
  o[0] = f2bf(a.x); o[1] = f2bf(a.y); o[2] = f2bf(a.z); o[3] = f2bf(a.w);
  o[4] = f2bf(b.x); o[5] = f2bf(b.y); o[6] = f2bf(b.z); o[7] = f2bf(b.w);
  *(u16x8*)(xb + i) = o;
}

// ---------------- prep: transpose+cvt all experts ----------------
__global__ void transpose_all_kernel(const float* __restrict__ Wg,
                                     const float* __restrict__ Wv,
                                     const float* __restrict__ Wo,
                                     u16* __restrict__ wgvT, u16* __restrict__ woT2) {
  __shared__ float lds[64][65];
  const int bid = blockIdx.x;           // 24576 = 8e * 3mat * 1024 tiles
  const int e = bid / 3072;
  const int r = bid % 3072;
  const int which = r >> 10;            // 0=Wg 1=Wv 2=Wo
  const int tt = r & 1023;
  const float* src; int R, C;
  if (which == 2) { src = Wo + (size_t)e * HDIM * DDIM; R = HDIM; C = DDIM; }
  else            { src = (which ? Wv : Wg) + (size_t)e * DDIM * HDIM; R = DDIM; C = HDIM; }
  const int nrt = R >> 6;
  const int r0 = (tt % nrt) << 6, c0 = (tt / nrt) << 6;
  const int tid = threadIdx.x;
#pragma unroll
  for (int i = 0; i < 4; ++i) {
    int f4 = tid + 256 * i;
    int row = f4 >> 4, c4 = (f4 & 15) << 2;
    float4 v = *(const float4*)(src + (size_t)(r0 + row) * C + c0 + c4);
    lds[row][c4] = v.x; lds[row][c4 + 1] = v.y; lds[row][c4 + 2] = v.z; lds[row][c4 + 3] = v.w;
  }
  __syncthreads();
#pragma unroll
  for (int i = 0; i < 4; ++i) {
    int f4 = tid + 256 * i;
    int cc = f4 >> 4, r4 = (f4 & 15) << 2;
    u16x4 o;
    o[0] = f2bf(lds[r4][cc]);     o[1] = f2bf(lds[r4 + 1][cc]);
    o[2] = f2bf(lds[r4 + 2][cc]); o[3] = f2bf(lds[r4 + 3][cc]);
    u16* dst;
    if (which == 2) {
      dst = woT2 + (size_t)(c0 + cc) * KTOT + e * HDIM + r0 + r4;
    } else {
      int h = c0 + cc;
      int rowp = ((h >> 4) << 5) + which * 16 + (h & 15);
      dst = wgvT + (size_t)e * NPRIME * DDIM + (size_t)rowp * DDIM + r0 + r4;
    }
    *(u16x4*)dst = o;
  }
}

// =================================================================
// GEMM core: BM=256, BN=256, BK=64, 8 waves (2M x 4N), wave tile 128x64.
// 2 LDS slots (64 KB each), 4-phase K-tile, TWO barriers/phase (WAR
// load-bearing), XOR-8 swizzle, strength-reduced read addresses.
// R9: IN-PLACE QUARTER-REPLACEMENT staging with 2-tile lead:
//   SA1(t+1)@p0(t), SA0(t+2)@p1(t), SB0(t+2)@p2(t), SB1(t+2)@p3(t)
// Each quarter is staged into a region whose last reads drained >=2
// barriers earlier (WAR ledger in round notes). Issue->drain distance
// for every unit is 6-7 phases (~2400 cyc) -> tolerates HBM latency.
// All RAW waits become uniform vmcnt(10) (queue = 12-14 loads, drains
// position-verified). Tail: staged-tile index clamps to NT-1 (re-stages
// identical bytes; value-identical race = safe), counts stay uniform.
// =================================================================

template<int KS>
__device__ __forceinline__ void gemm_loop(const u16* Ab, const u16* Bb,
                                          int Am0, int Bn0, int kbase, int NT,
                                          u16* lds, int tid, f32x4 (&acc)[8][4]) {
  const int lane = tid & 63;
  const int wave = tid >> 6;
  const int wm = wave >> 2, wn = wave & 3;
  const int l15 = lane & 15, lkq = lane >> 4;

  // ---- staging descriptors (per thread: 2 chunks per quarter-unit)
  const int sl = tid & 7, rw = tid >> 3;          // rw 0..63
  const int slx = (sl ^ (rw & 7)) << 3;           // inverse-swizzled k-offset
  const int rb = (rw & 31) + ((rw >> 5) << 6);    // B base row
  const u16* pA = Ab + (size_t)(Am0 + rw) * KS + kbase + slx;
  const u16* pB = Bb + (size_t)(Bn0 + rb) * KS + kbase + slx;
  const int dA = rw * 64 + sl * 8;
  const int dB = 16384 + rb * 64 + sl * 8;

  auto slot = [&](int t) -> u16* { return lds + (t & 1) * 32768; };
  auto SA0 = [&](int t) { u16* sp = slot(t); const int k = t << 6;
    stage16(pA + k, sp + dA);
    stage16(pA + (size_t)128 * KS + k, sp + dA + 8192); };
  auto SA1 = [&](int t) { u16* sp = slot(t); const int k = t << 6;
    stage16(pA + (size_t)64 * KS + k, sp + dA + 4096);
    stage16(pA + (size_t)192 * KS + k, sp + dA + 12288); };
  auto SB0 = [&](int t) { u16* sp = slot(t); const int k = t << 6;
    stage16(pB + k, sp + dB);
    stage16(pB + (size_t)128 * KS + k, sp + dB + 8192); };
  auto SB1 = [&](int t) { u16* sp = slot(t); const int k = t << 6;
    stage16(pB + (size_t)32 * KS + k, sp + dB + 2048);
    stage16(pB + (size_t)160 * KS + k, sp + dB + 10240); };

  // ---- strength-reduced read bases (elems). row&7 == l15&7 for all reads.
  const int swz0 = (lkq ^ (l15 & 7)) << 3;        // ks=0 slot
  const int swz1 = ((4 | lkq) ^ (l15 & 7)) << 3;  // ks=1 slot
  const int arow = (wm * 128 + l15) * 64;
  const int brow = 16384 + (wn * 64 + l15) * 64;
  const int a0 = arow + swz0, a1 = arow + swz1;
  const int b0 = brow + swz0, b1 = brow + swz1;

  // prologue: tile 0 fully + tile 1's first three quarters (14 loads).
  // vmcnt(10) drains SA0(0),SB0(0) -> resident after barrier.
  SA0(0); SB0(0); SB1(0); SA1(0);
  SA0(1); SB0(1); SB1(1);
  asm volatile("s_waitcnt vmcnt(10)" ::: "memory");
  __builtin_amdgcn_s_barrier();

#pragma unroll 1
  for (int t = 0; t < NT; ++t) {
    const u16* s = slot(t);
    const int tp1 = (t + 1 < NT) ? t + 1 : NT - 1;   // clamp keeps counts uniform
    const int tp2 = (t + 2 < NT) ? t + 2 : NT - 1;
    bf16x8 af[4][2], bfr[4][2];

    // ---------- phase 0: read A-mh0 + B-nh0 ; stage SA1(t+1) ; MFMA m0-3 x n0-1
#pragma unroll
    for (int mf = 0; mf < 4; ++mf) {
      af[mf][0] = *(const bf16x8*)(s + a0 + mf * 1024);
      af[mf][1] = *(const bf16x8*)(s + a1 + mf * 1024);
    }
#pragma unroll
    for (int nf = 0; nf < 2; ++nf) {
      bfr[nf][0] = *(const bf16x8*)(s + b0 + nf * 1024);
      bfr[nf][1] = *(const bf16x8*)(s + b1 + nf * 1024);
    }
    SA1(tp1);
    asm volatile("s_waitcnt vmcnt(10)" ::: "memory");   // drains SB1(t)
    __builtin_amdgcn_s_barrier();
    asm volatile("s_waitcnt lgkmcnt(0)" ::: "memory");
    __builtin_amdgcn_sched_barrier(0);
    __builtin_amdgcn_s_setprio(1);
#pragma unroll
    for (int ks = 0; ks < 2; ++ks)
#pragma unroll
      for (int mf = 0; mf < 4; ++mf)
#pragma unroll
        for (int nf = 0; nf < 2; ++nf)
          acc[mf][nf] = __builtin_amdgcn_mfma_f32_16x16x32_bf16(af[mf][ks], bfr[nf][ks], acc[mf][nf], 0, 0, 0);
    __builtin_amdgcn_s_setprio(0);
    __builtin_amdgcn_s_barrier();

    // ---------- phase 1: read B-nh1 ; stage SA0(t+2) ; MFMA m0-3 x n2-3
#pragma unroll
    for (int nf = 2; nf < 4; ++nf) {
      bfr[nf][0] = *(const bf16x8*)(s + b0 + nf * 1024);
      bfr[nf][1] = *(const bf16x8*)(s + b1 + nf * 1024);
    }
    SA0(tp2);
    asm volatile("s_waitcnt vmcnt(10)" ::: "memory");   // drains SA1(t)
    __builtin_amdgcn_s_barrier();
    asm volatile("s_waitcnt lgkmcnt(0)" ::: "memory");
    __builtin_amdgcn_sched_barrier(0);
    __builtin_amdgcn_s_setprio(1);
#pragma unroll
    for (int ks = 0; ks < 2; ++ks)
#pragma unroll
      for (int mf = 0; mf < 4; ++mf)
#pragma unroll
        for (int nf = 2; nf < 4; ++nf)
          acc[mf][nf] = __builtin_amdgcn_mfma_f32_16x16x32_bf16(af[mf][ks], bfr[nf][ks], acc[mf][nf], 0, 0, 0);
    __builtin_amdgcn_s_setprio(0);
    __builtin_amdgcn_s_barrier();

    // ---------- phase 2: read A-mh1 ; stage SB0(t+2) ; MFMA m4-7 x n0-1
#pragma unroll
    for (int mf = 0; mf < 4; ++mf) {
      af[mf][0] = *(const bf16x8*)(s + a0 + 4096 + mf * 1024);
      af[mf][1] = *(const bf16x8*)(s + a1 + 4096 + mf * 1024);
    }
    SB0(tp2);
    __builtin_amdgcn_s_barrier();
    asm volatile("s_waitcnt lgkmcnt(0)" ::: "memory");
    __builtin_amdgcn_sched_barrier(0);
    __builtin_amdgcn_s_setprio(1);
#pragma unroll
    for (int ks = 0; ks < 2; ++ks)
#pragma unroll
      for (int mf = 0; mf < 4; ++mf)
#pragma unroll
        for (int nf = 0; nf < 2; ++nf)
          acc[4 + mf][nf] = __builtin_amdgcn_mfma_f32_16x16x32_bf16(af[mf][ks], bfr[nf][ks], acc[4 + mf][nf], 0, 0, 0);
    __builtin_amdgcn_s_setprio(0);
    __builtin_amdgcn_s_barrier();

    // ---------- phase 3: stage SB1(t+2) ; MFMA m4-7 x n2-3 (regs cached)
    SB1(tp2);
    asm volatile("s_waitcnt vmcnt(10)" ::: "memory");   // drains SA0(t+1),SB0(t+1)
    __builtin_amdgcn_s_barrier();
    __builtin_amdgcn_s_setprio(1);
#pragma unroll
    for (int ks = 0; ks < 2; ++ks)
#pragma unroll
      for (int mf = 0; mf < 4; ++mf)
#pragma unroll
        for (int nf = 2; nf < 4; ++nf)
          acc[4 + mf][nf] = __builtin_amdgcn_mfma_f32_16x16x32_bf16(af[mf][ks], bfr[nf][ks], acc[4 + mf][nf], 0, 0, 0);
    __builtin_amdgcn_s_setprio(0);
    __builtin_amdgcn_s_barrier();
  }
}

// ---------------- GEMM A: h = (gelu(x@Wg) * (x@Wv)) * scale * cw ----------------
__global__ void __launch_bounds__(512, 2)
gemm_gv_kernel(const u16* __restrict__ xb, const u16* __restrict__ wgvT,
               const float* __restrict__ disp, const float* __restrict__ comb,
               const float* __restrict__ scale, u16* __restrict__ h) {
  __shared__ u16 lds[65536];

  // XCD swizzle: 2048 wgs, expert e -> XCD e
  const int bid = blockIdx.x;
  const int wg = (bid & 7) * 256 + (bid >> 3);
  const int e  = wg >> 8;
  const int rr = wg & 255;
  const int nt = rr >> 3;          // 0..31 (N' tiles of 256)
  const int mt = rr & 7;           // 0..7  (M tiles of 256)

  const int tid = threadIdx.x;
  const int lane = tid & 63;
  const int wave = tid >> 6;
  const int wm = wave >> 2, wn = wave & 3;
  const int l15 = lane & 15, lkq = lane >> 4;

  const u16* Bb = wgvT + (size_t)e * NPRIME * DDIM;
  const int Am0 = mt * 256;
  const int Bn0 = nt * 256;

  f32x4 acc[8][4] = {};
  gemm_loop<DDIM>(xb, Bb, Am0, Bn0, 0, DDIM / 64, lds, tid, acc);

  const float s_e = scale[e];
  const int hbase = nt * 128 + wn * 32;   // H-col base within expert
#pragma unroll
  for (int a = 0; a < 8; ++a) {
#pragma unroll
    for (int r = 0; r < 4; ++r) {
      const int t = Am0 + wm * 128 + a * 16 + lkq * 4 + r;
      const float dv = disp[t * NEXP + e];
      const float cv = comb[t * NEXP + e];
      const float s = (dv > 0.0f) ? cv * s_e : 0.0f;
#pragma unroll
      for (int jj = 0; jj < 2; ++jj) {
        const float g = acc[a][2 * jj][r];
        const float v = acc[a][2 * jj + 1][r];
        const float ge = 0.5f * g * (1.0f + erff(g * 0.70710678f));
        h[(size_t)t * KTOT + e * HDIM + hbase + jj * 16 + l15] = f2bf(ge * v * s);
      }
    }
  }
}

// ---------------- GEMM B: P[kz] = h[T][EH] @ woT2[D][EH]^T (split-K 8) ----------------
__global__ void __launch_bounds__(512, 2)
gemm_out_kernel(const u16* __restrict__ hb, const u16* __restrict__ woT2,
                float* __restrict__ P) {
  __shared__ u16 lds[65536];

  const int bid = blockIdx.x;          // 256 wgs
  const int wg = (bid & 7) * 32 + (bid >> 3);
  const int kz = wg >> 5;              // 0..7, one per XCD
  const int rr = wg & 31;
  const int nt = rr >> 3;              // 0..3 (D tiles of 256)
  const int mt = rr & 7;               // 0..7 (token tiles of 256)

  const int tid = threadIdx.x;
  const int lane = tid & 63;
  const int wave = tid >> 6;
  const int wm = wave >> 2, wn = wave & 3;
  const int l15 = lane & 15, lkq = lane >> 4;

  const int Am0 = mt * 256;
  const int Bn0 = nt * 256;
  const int kbase = kz * (KTOT / NSPLIT);   // 4096 per split

  f32x4 acc[8][4] = {};
  gemm_loop<KTOT>(hb, woT2, Am0, Bn0, kbase, (KTOT / NSPLIT) / 64, lds, tid, acc);

  float* Pp = P + (size_t)kz * (T_TOK * DDIM);
#pragma unroll
  for (int a = 0; a < 8; ++a) {
#pragma unroll
    for (int r = 0; r < 4; ++r) {
      const int t = Am0 + wm * 128 + a * 16 + lkq * 4 + r;
#pragma unroll
      for (int nf = 0; nf < 4; ++nf)
        Pp[(size_t)t * DDIM + Bn0 + wn * 64 + nf * 16 + l15] = acc[a][nf][r];
    }
  }
}

// ---------------- final: out = sum of NSPLIT partials ----------------
__global__ void reduce_out_kernel(const float* __restrict__ P, float* __restrict__ out) {
  int i = blockIdx.x * 256 + threadIdx.x;
  float4 a = ((const float4*)P)[i];
#pragma unroll
  for (int s = 1; s < NSPLIT; ++s) {
    float4 b = ((const float4*)P)[i + s * (T_TOK * DDIM / 4)];
    a.x += b.x; a.y += b.y; a.z += b.z; a.w += b.w;
  }
  ((float4*)out)[i] = a;
}

extern "C" void kernel_launch(void* const* d_in, const int* in_sizes, int n_in,
                              void* d_out, int out_size, void* d_ws, size_t ws_size,
                              hipStream_t stream) {
  const float* tokens = (const float*)d_in[0];
  const float* disp   = (const float*)d_in[1];
  const float* comb   = (const float*)d_in[2];
  const float* Wg     = (const float*)d_in[3];
  const float* Wv     = (const float*)d_in[4];
  const float* Wo     = (const float*)d_in[5];
  const float* scale  = (const float*)d_in[6];
  float* out = (float*)d_out;

  char* ws = (char*)d_ws;
  const size_t MB = 1024 * 1024;
  u16* xb    = (u16*)(ws);              // 4 MB   [T][D] bf16
  u16* wgvT  = (u16*)(ws + 4   * MB);   // 128 MB [E][8192][D] interleaved g/v
  u16* woT2  = (u16*)(ws + 132 * MB);   // 64 MB  [D][E*H]
  u16* hbuf  = (u16*)(ws + 196 * MB);   // 128 MB [T][E*H]
  float* P   = (float*)(ws + 324 * MB); // 64 MB  NSPLIT x [T][D] fp32

  cvt_x_kernel<<<1024, 256, 0, stream>>>(tokens, xb);
  transpose_all_kernel<<<24576, 256, 0, stream>>>(Wg, Wv, Wo, wgvT, woT2);
  gemm_gv_kernel<<<2048, 512, 0, stream>>>(xb, wgvT, disp, comb, scale, hbuf);
  gemm_out_kernel<<<256, 512, 0, stream>>>(hbuf, woT2, P);
  reduce_out_kernel<<<2048, 256, 0, stream>>>(P, out);
}